// Round 6
// baseline (37.834 us; speedup 1.0000x reference)
//
#include <hip/hip_runtime.h>

#define BB 16
#define NN 6000
#define GG 512
#define WAVES 4

// ---- workspace layout ----
// float4 boxes [BB][GG]               : BB*GG*16 bytes
// float  areas [BB][GG] (16B aligned) : BB*GG*4  bytes
// int    cnt   [BB][2] = {nc_eff, lo_pad}
#define WS_BOX_OFF   0
#define WS_AREA_OFF  (BB * GG * 16)
#define WS_CNT_OFF   (BB * GG * 20)
#define WS_NEEDED    (WS_CNT_OFF + BB * 8)

__global__ __launch_bounds__(256) void compact_kernel(
    const int*    __restrict__ gt_ids,    // (B, G)
    const float4* __restrict__ gt_boxes,  // (B, G, 4)
    float4*       __restrict__ ws_box,    // (B, G)
    float*        __restrict__ ws_area,   // (B, G)
    int*          __restrict__ ws_cnt)    // (B, 2)
{
    __shared__ int s_cnt[2];
    const int b   = blockIdx.x;
    const int tid = threadIdx.x;
    if (tid == 0) { s_cnt[0] = 0; s_cnt[1] = 0; }
    __syncthreads();

    for (int g = tid; g < GG; g += 256) {
        float4 box = gt_boxes[b * GG + g];
        float asum = fabsf(box.x) + fabsf(box.y) + fabsf(box.z) + fabsf(box.w);
        int id = gt_ids[b * GG + g];
        if (asum > 0.0f && id != 0) {
            int idx;
            if (id > 0) idx = atomicAdd(&s_cnt[0], 1);            // non-crowd: front
            else        idx = (GG - 1) - atomicAdd(&s_cnt[1], 1); // crowd: back
            ws_box[b * GG + idx]  = box;
            ws_area[b * GG + idx] = (box.z - box.x) * (box.w - box.y);
        }
    }
    __syncthreads();

    if (tid == 0) {
        const int ncnt = s_cnt[0];
        const int ccnt = s_cnt[1];
        int nc_eff = (ncnt + 3) & ~3;          // pad nc list up to x4
        const int lo     = GG - ccnt;
        int lo_pad = lo & ~3;                  // pad crowd list down to x4
        if (nc_eff > lo_pad) nc_eff = lo_pad;  // safety (can't happen with this data)
        const float4 z = make_float4(0.f, 0.f, 0.f, 0.f);
        for (int i = ncnt; i < nc_eff; ++i) { ws_box[b * GG + i] = z; ws_area[b * GG + i] = 0.f; }
        for (int i = lo_pad; i < lo; ++i)   { ws_box[b * GG + i] = z; ws_area[b * GG + i] = 0.f; }
        ws_cnt[b * 2 + 0] = nc_eff;   // nc list = [0, nc_eff), multiple of 4
        ws_cnt[b * 2 + 1] = lo_pad;   // crowd list = [lo_pad, GG), multiple of 4
    }
}

__global__ __launch_bounds__(64 * WAVES) void det_main_kernel(
    const float4* __restrict__ rois,      // (B, N, 4)
    const float4* __restrict__ ws_box,    // compacted, padded
    const float*  __restrict__ ws_area,   // compacted, padded, 16B aligned
    const int*    __restrict__ ws_cnt,
    float*        __restrict__ out)
{
    __shared__ float s_ncm[WAVES][64];
    __shared__ float s_cm[WAVES][64];

    const int b    = blockIdx.y;
    const int tid  = threadIdx.x;
    const int wave = tid >> 6;
    const int lane = tid & 63;

    // Uniform (scalar) GT metadata
    const int nc_eff = ws_cnt[b * 2 + 0];
    const int lo_pad = ws_cnt[b * 2 + 1];

    const int n = blockIdx.x * 64 + lane;
    const float4 r = (n < NN) ? rois[b * NN + n] : make_float4(0.f, 0.f, 0.f, 0.f);
    const bool vroi = (fabsf(r.x) + fabsf(r.y) + fabsf(r.z) + fabsf(r.w)) > 0.0f;
    const float rsum = (r.z - r.x) * (r.w - r.y) + 1e-8f;

    const float4* __restrict__ gb  = ws_box + b * GG;           // uniform-indexed -> s_load
    const float4* __restrict__ ga4 = (const float4*)(ws_area + b * GG);

    auto iou_of = [&](float4 g4, float ga) -> float {
        float yy1 = fmaxf(r.x, g4.x);
        float xx1 = fmaxf(r.y, g4.y);
        float yy2 = fminf(r.z, g4.z);
        float xx2 = fminf(r.w, g4.w);
        float inter = fmaxf(yy2 - yy1, 0.0f) * fmaxf(xx2 - xx1, 0.0f);
        float uni = rsum + ga - inter;
        return inter * __builtin_amdgcn_rcpf(uni);
    };

    // --- Non-crowd: groups of 4, split across waves ---
    float ncm = 0.0f;
    {
        const int ngr = nc_eff >> 2;
        const int gpw = (ngr + WAVES - 1) / WAVES;
        const int q0 = wave * gpw;
        const int q1 = min(ngr, q0 + gpw);
        for (int q = q0; q < q1; ++q) {
            float4 b0 = gb[4 * q + 0];
            float4 b1 = gb[4 * q + 1];
            float4 b2 = gb[4 * q + 2];
            float4 b3 = gb[4 * q + 3];
            float4 a4 = ga4[q];
            float i0 = iou_of(b0, a4.x);
            float i1 = iou_of(b1, a4.y);
            float i2 = iou_of(b2, a4.z);
            float i3 = iou_of(b3, a4.w);
            ncm = fmaxf(ncm, fmaxf(fmaxf(i0, i1), fmaxf(i2, i3)));
        }
    }

    // --- Crowd: groups [lo_pad/4, GG/4), split across waves ---
    float cm = 0.0f;
    {
        const int cg0 = lo_pad >> 2;
        const int cgn = (GG >> 2) - cg0;
        const int gpw = (cgn + WAVES - 1) / WAVES;
        const int q0 = cg0 + wave * gpw;
        const int q1 = min(GG >> 2, q0 + gpw);
        for (int q = q0; q < q1; ++q) {
            float4 b0 = gb[4 * q + 0];
            float4 b1 = gb[4 * q + 1];
            float4 b2 = gb[4 * q + 2];
            float4 b3 = gb[4 * q + 3];
            float4 a4 = ga4[q];
            float i0 = iou_of(b0, a4.x);
            float i1 = iou_of(b1, a4.y);
            float i2 = iou_of(b2, a4.z);
            float i3 = iou_of(b3, a4.w);
            cm = fmaxf(cm, fmaxf(fmaxf(i0, i1), fmaxf(i2, i3)));
        }
    }

    s_ncm[wave][lane] = ncm;
    s_cm[wave][lane]  = cm;
    __syncthreads();

    if (wave == 0 && n < NN) {
        float a = s_ncm[0][lane], c = s_cm[0][lane];
        #pragma unroll
        for (int w = 1; w < WAVES; ++w) {
            a = fmaxf(a, s_ncm[w][lane]);
            c = fmaxf(c, s_cm[w][lane]);
        }
        const float nc_max = vroi ? a : 0.0f;
        const float c_max  = vroi ? c : 0.0f;

        out[b * 2 * NN + n]      = nc_max;     // iou_maxes (B,2,N) ch0
        out[b * 2 * NN + NN + n] = c_max;      // iou_maxes (B,2,N) ch1
        const float pos = (vroi && nc_max >= 0.5f) ? 1.0f : 0.0f;
        const float neg = (vroi && nc_max < 0.5f && c_max < 0.001f) ? 1.0f : 0.0f;
        out[BB * 2 * NN + b * NN + n]           = pos;
        out[BB * 2 * NN + BB * NN + b * NN + n] = neg;
    }
}

// ---------- fallback (R4, passed @27us): self-contained single kernel ----------
__global__ __launch_bounds__(256) void det_assign_fallback(
    const float4* __restrict__ rois,
    const int*    __restrict__ gt_ids,
    const float4* __restrict__ gt_boxes,
    float*        __restrict__ out)
{
    __shared__ float4 s_box[GG];
    __shared__ float4 s_area4[GG / 4];
    __shared__ float  s_ncm[4][64];
    __shared__ float  s_cm[4][64];
    __shared__ int    s_cnt[2];
    float* s_area = (float*)s_area4;

    const int b    = blockIdx.y;
    const int tid  = threadIdx.x;
    const int wave = tid >> 6;
    const int lane = tid & 63;

    if (tid == 0) { s_cnt[0] = 0; s_cnt[1] = 0; }
    __syncthreads();
    for (int g = tid; g < GG; g += 256) {
        float4 box = gt_boxes[b * GG + g];
        float asum = fabsf(box.x) + fabsf(box.y) + fabsf(box.z) + fabsf(box.w);
        int id = gt_ids[b * GG + g];
        if (asum > 0.0f && id != 0) {
            int idx;
            if (id > 0) idx = atomicAdd(&s_cnt[0], 1);
            else        idx = (GG - 1) - atomicAdd(&s_cnt[1], 1);
            s_box[idx]  = box;
            s_area[idx] = (box.z - box.x) * (box.w - box.y);
        }
    }
    __syncthreads();

    const int n = blockIdx.x * 64 + lane;
    const float4 r = (n < NN) ? rois[b * NN + n] : make_float4(0.f, 0.f, 0.f, 0.f);
    const bool vroi = (fabsf(r.x) + fabsf(r.y) + fabsf(r.z) + fabsf(r.w)) > 0.0f;
    const float rsum = (r.z - r.x) * (r.w - r.y) + 1e-8f;
    const int ncnt = __builtin_amdgcn_readfirstlane(s_cnt[0]);
    const int ccnt = __builtin_amdgcn_readfirstlane(s_cnt[1]);

    auto iou_of = [&](float4 g4, float ga) -> float {
        float yy1 = fmaxf(r.x, g4.x);
        float xx1 = fmaxf(r.y, g4.y);
        float yy2 = fminf(r.z, g4.z);
        float xx2 = fminf(r.w, g4.w);
        float inter = fmaxf(yy2 - yy1, 0.0f) * fmaxf(xx2 - xx1, 0.0f);
        return inter * __builtin_amdgcn_rcpf(rsum + ga - inter);
    };

    float ncm = 0.0f;
    {
        const int chunk = (((ncnt + 3) >> 2) + 3) & ~3;
        const int g0 = wave * chunk;
        const int g1 = min(ncnt, g0 + chunk);
        for (int g = g0; g < g1; ++g) ncm = fmaxf(ncm, iou_of(s_box[g], s_area[g]));
    }
    float cm = 0.0f;
    {
        const int chunkc = (((ccnt + 3) >> 2) + 3) & ~3;
        const int hi = GG - wave * chunkc;
        const int lo = max(GG - ccnt, hi - chunkc);
        for (int g = lo; g < hi; ++g) cm = fmaxf(cm, iou_of(s_box[g], s_area[g]));
    }
    s_ncm[wave][lane] = ncm;
    s_cm[wave][lane]  = cm;
    __syncthreads();
    if (wave == 0 && n < NN) {
        float a = fmaxf(fmaxf(s_ncm[0][lane], s_ncm[1][lane]),
                        fmaxf(s_ncm[2][lane], s_ncm[3][lane]));
        float c = fmaxf(fmaxf(s_cm[0][lane], s_cm[1][lane]),
                        fmaxf(s_cm[2][lane], s_cm[3][lane]));
        const float nc_max = vroi ? a : 0.0f;
        const float c_max  = vroi ? c : 0.0f;
        out[b * 2 * NN + n]      = nc_max;
        out[b * 2 * NN + NN + n] = c_max;
        const float pos = (vroi && nc_max >= 0.5f) ? 1.0f : 0.0f;
        const float neg = (vroi && nc_max < 0.5f && c_max < 0.001f) ? 1.0f : 0.0f;
        out[BB * 2 * NN + b * NN + n]           = pos;
        out[BB * 2 * NN + BB * NN + b * NN + n] = neg;
    }
}

extern "C" void kernel_launch(void* const* d_in, const int* in_sizes, int n_in,
                              void* d_out, int out_size, void* d_ws, size_t ws_size,
                              hipStream_t stream) {
    const float4* rois     = (const float4*)d_in[0];
    const int*    gt_ids   = (const int*)d_in[1];
    const float4* gt_boxes = (const float4*)d_in[2];
    float*        out      = (float*)d_out;

    if (ws_size >= (size_t)WS_NEEDED) {
        char* ws = (char*)d_ws;
        float4* ws_box  = (float4*)(ws + WS_BOX_OFF);
        float*  ws_area = (float*)(ws + WS_AREA_OFF);
        int*    ws_cnt  = (int*)(ws + WS_CNT_OFF);

        compact_kernel<<<BB, 256, 0, stream>>>(gt_ids, gt_boxes, ws_box, ws_area, ws_cnt);
        dim3 grid((NN + 63) / 64, BB);
        det_main_kernel<<<grid, 64 * WAVES, 0, stream>>>(
            rois, ws_box, ws_area, ws_cnt, out);
    } else {
        dim3 grid((NN + 63) / 64, BB);
        det_assign_fallback<<<grid, 256, 0, stream>>>(rois, gt_ids, gt_boxes, out);
    }
}

// Round 7
// 31.050 us; speedup vs baseline: 1.2185x; 1.2185x over previous
//
#include <hip/hip_runtime.h>

#define BB 16
#define NN 6000
#define GG 512
#define WAVES 8

typedef __attribute__((ext_vector_type(16))) float f32x16;
typedef __attribute__((ext_vector_type(4)))  float f32x4;

// ---- workspace layout ----
// float4 boxes [BB][GG]               : BB*GG*16 bytes
// float  areas [BB][GG] (16B aligned) : BB*GG*4  bytes
// int    cnt   [BB][2] = {nc_eff, lo_pad}
#define WS_BOX_OFF   0
#define WS_AREA_OFF  (BB * GG * 16)
#define WS_CNT_OFF   (BB * GG * 20)
#define WS_NEEDED    (WS_CNT_OFF + BB * 8)

__global__ __launch_bounds__(256) void compact_kernel(
    const int*    __restrict__ gt_ids,    // (B, G)
    const float4* __restrict__ gt_boxes,  // (B, G, 4)
    float4*       __restrict__ ws_box,    // (B, G)
    float*        __restrict__ ws_area,   // (B, G)
    int*          __restrict__ ws_cnt)    // (B, 2)
{
    __shared__ int s_cnt[2];
    const int b   = blockIdx.x;
    const int tid = threadIdx.x;
    if (tid == 0) { s_cnt[0] = 0; s_cnt[1] = 0; }
    __syncthreads();

    for (int g = tid; g < GG; g += 256) {
        float4 box = gt_boxes[b * GG + g];
        float asum = fabsf(box.x) + fabsf(box.y) + fabsf(box.z) + fabsf(box.w);
        int id = gt_ids[b * GG + g];
        if (asum > 0.0f && id != 0) {
            int idx;
            if (id > 0) idx = atomicAdd(&s_cnt[0], 1);            // non-crowd: front
            else        idx = (GG - 1) - atomicAdd(&s_cnt[1], 1); // crowd: back
            ws_box[b * GG + idx]  = box;
            ws_area[b * GG + idx] = (box.z - box.x) * (box.w - box.y);
        }
    }
    __syncthreads();

    if (tid == 0) {
        const int ncnt = s_cnt[0];
        const int ccnt = s_cnt[1];
        int nc_eff = (ncnt + 3) & ~3;          // pad nc list up to x4
        const int lo = GG - ccnt;
        int lo_pad = lo & ~3;                  // pad crowd list down to x4
        if (nc_eff > lo_pad) nc_eff = lo_pad;  // safety
        const float4 z = make_float4(0.f, 0.f, 0.f, 0.f);
        for (int i = ncnt; i < nc_eff; ++i) { ws_box[b * GG + i] = z; ws_area[b * GG + i] = 0.f; }
        for (int i = lo_pad; i < lo; ++i)   { ws_box[b * GG + i] = z; ws_area[b * GG + i] = 0.f; }
        ws_cnt[b * 2 + 0] = nc_eff;   // nc list = [0, nc_eff), multiple of 4
        ws_cnt[b * 2 + 1] = lo_pad;   // crowd list = [lo_pad, GG), multiple of 4
    }
}

__global__ __launch_bounds__(64 * WAVES) void det_main_kernel(
    const float4* __restrict__ rois,      // (B, N, 4)
    const float4* __restrict__ ws_box,    // compacted, padded
    const float*  __restrict__ ws_area,   // compacted, padded, 16B aligned
    const int*    __restrict__ ws_cnt,
    float*        __restrict__ out)
{
    __shared__ float s_ncm[WAVES][64];
    __shared__ float s_cm[WAVES][64];

    const int b    = blockIdx.y;
    const int tid  = threadIdx.x;
    const int wave = tid >> 6;
    const int lane = tid & 63;

    const int nc_eff = ws_cnt[b * 2 + 0];   // uniform
    const int lo_pad = ws_cnt[b * 2 + 1];

    const int n = blockIdx.x * 64 + lane;
    const float4 r = (n < NN) ? rois[b * NN + n] : make_float4(0.f, 0.f, 0.f, 0.f);
    const bool vroi = (fabsf(r.x) + fabsf(r.y) + fabsf(r.z) + fabsf(r.w)) > 0.0f;
    const float rsum = (r.z - r.x) * (r.w - r.y) + 1e-8f;

    const char* gbase = (const char*)(ws_box + b * GG);
    const char* abase = (const char*)(ws_area + b * GG);

    // IoU from SGPR-held GT box (bx = y1,x1,y2,x2), SGPR area ga
    auto iou_of = [&](float gy1, float gx1, float gy2, float gx2, float ga) -> float {
        float yy1 = fmaxf(r.x, gy1);
        float xx1 = fmaxf(r.y, gx1);
        float yy2 = fminf(r.z, gy2);
        float xx2 = fminf(r.w, gx2);
        float inter = fmaxf(yy2 - yy1, 0.0f) * fmaxf(xx2 - xx1, 0.0f);
        float uni = rsum + ga - inter;
        return inter * __builtin_amdgcn_rcpf(uni);
    };

    // Process groups of 4 GTs via scalar loads: boxes (64B) + areas (16B)
    auto run_range = [&](int q0, int q1, float& acc) {
        for (int q = q0; q < q1; ++q) {
            unsigned long long pb = (unsigned long long)(gbase + (size_t)q * 64);
            unsigned long long pa = (unsigned long long)(abase + (size_t)q * 16);
            f32x16 bx;
            f32x4  ar;
            asm volatile(
                "s_load_dwordx16 %0, %2, 0x0\n\t"
                "s_load_dwordx4  %1, %3, 0x0\n\t"
                "s_waitcnt lgkmcnt(0)"
                : "=&s"(bx), "=&s"(ar)
                : "s"(pb), "s"(pa));
            __builtin_amdgcn_sched_barrier(0);
            float i0 = iou_of(bx[0],  bx[1],  bx[2],  bx[3],  ar[0]);
            float i1 = iou_of(bx[4],  bx[5],  bx[6],  bx[7],  ar[1]);
            float i2 = iou_of(bx[8],  bx[9],  bx[10], bx[11], ar[2]);
            float i3 = iou_of(bx[12], bx[13], bx[14], bx[15], ar[3]);
            acc = fmaxf(acc, fmaxf(fmaxf(i0, i1), fmaxf(i2, i3)));
        }
    };

    // --- Non-crowd: groups [0, nc_eff/4) split across waves, scalar bounds ---
    float ncm = 0.0f;
    {
        const int ngr = nc_eff >> 2;
        const int gpw = (ngr + WAVES - 1) / WAVES;
        const int q0  = __builtin_amdgcn_readfirstlane(wave * gpw);
        const int q1  = min(ngr, q0 + gpw);
        run_range(q0, q1, ncm);
    }

    // --- Crowd: groups [lo_pad/4, GG/4) split across waves ---
    float cm = 0.0f;
    {
        const int cg0 = lo_pad >> 2;
        const int cgn = (GG >> 2) - cg0;
        const int gpw = (cgn + WAVES - 1) / WAVES;
        const int q0  = __builtin_amdgcn_readfirstlane(cg0 + wave * gpw);
        const int q1  = min(GG >> 2, q0 + gpw);
        run_range(q0, q1, cm);
    }

    s_ncm[wave][lane] = ncm;
    s_cm[wave][lane]  = cm;
    __syncthreads();

    if (wave == 0 && n < NN) {
        float a = s_ncm[0][lane], c = s_cm[0][lane];
        #pragma unroll
        for (int w = 1; w < WAVES; ++w) {
            a = fmaxf(a, s_ncm[w][lane]);
            c = fmaxf(c, s_cm[w][lane]);
        }
        const float nc_max = vroi ? a : 0.0f;
        const float c_max  = vroi ? c : 0.0f;

        out[b * 2 * NN + n]      = nc_max;     // iou_maxes (B,2,N) ch0
        out[b * 2 * NN + NN + n] = c_max;      // iou_maxes (B,2,N) ch1
        const float pos = (vroi && nc_max >= 0.5f) ? 1.0f : 0.0f;
        const float neg = (vroi && nc_max < 0.5f && c_max < 0.001f) ? 1.0f : 0.0f;
        out[BB * 2 * NN + b * NN + n]           = pos;
        out[BB * 2 * NN + BB * NN + b * NN + n] = neg;
    }
}

// ---------- fallback (R4, passed @27us): self-contained single kernel ----------
__global__ __launch_bounds__(256) void det_assign_fallback(
    const float4* __restrict__ rois,
    const int*    __restrict__ gt_ids,
    const float4* __restrict__ gt_boxes,
    float*        __restrict__ out)
{
    __shared__ float4 s_box[GG];
    __shared__ float4 s_area4[GG / 4];
    __shared__ float  s_ncm[4][64];
    __shared__ float  s_cm[4][64];
    __shared__ int    s_cnt[2];
    float* s_area = (float*)s_area4;

    const int b    = blockIdx.y;
    const int tid  = threadIdx.x;
    const int wave = tid >> 6;
    const int lane = tid & 63;

    if (tid == 0) { s_cnt[0] = 0; s_cnt[1] = 0; }
    __syncthreads();
    for (int g = tid; g < GG; g += 256) {
        float4 box = gt_boxes[b * GG + g];
        float asum = fabsf(box.x) + fabsf(box.y) + fabsf(box.z) + fabsf(box.w);
        int id = gt_ids[b * GG + g];
        if (asum > 0.0f && id != 0) {
            int idx;
            if (id > 0) idx = atomicAdd(&s_cnt[0], 1);
            else        idx = (GG - 1) - atomicAdd(&s_cnt[1], 1);
            s_box[idx]  = box;
            s_area[idx] = (box.z - box.x) * (box.w - box.y);
        }
    }
    __syncthreads();

    const int n = blockIdx.x * 64 + lane;
    const float4 r = (n < NN) ? rois[b * NN + n] : make_float4(0.f, 0.f, 0.f, 0.f);
    const bool vroi = (fabsf(r.x) + fabsf(r.y) + fabsf(r.z) + fabsf(r.w)) > 0.0f;
    const float rsum = (r.z - r.x) * (r.w - r.y) + 1e-8f;
    const int ncnt = __builtin_amdgcn_readfirstlane(s_cnt[0]);
    const int ccnt = __builtin_amdgcn_readfirstlane(s_cnt[1]);

    auto iou_of = [&](float4 g4, float ga) -> float {
        float yy1 = fmaxf(r.x, g4.x);
        float xx1 = fmaxf(r.y, g4.y);
        float yy2 = fminf(r.z, g4.z);
        float xx2 = fminf(r.w, g4.w);
        float inter = fmaxf(yy2 - yy1, 0.0f) * fmaxf(xx2 - xx1, 0.0f);
        return inter * __builtin_amdgcn_rcpf(rsum + ga - inter);
    };

    float ncm = 0.0f;
    {
        const int chunk = (((ncnt + 3) >> 2) + 3) & ~3;
        const int g0 = wave * chunk;
        const int g1 = min(ncnt, g0 + chunk);
        for (int g = g0; g < g1; ++g) ncm = fmaxf(ncm, iou_of(s_box[g], s_area[g]));
    }
    float cm = 0.0f;
    {
        const int chunkc = (((ccnt + 3) >> 2) + 3) & ~3;
        const int hi = GG - wave * chunkc;
        const int lo = max(GG - ccnt, hi - chunkc);
        for (int g = lo; g < hi; ++g) cm = fmaxf(cm, iou_of(s_box[g], s_area[g]));
    }
    s_ncm[wave][lane] = ncm;
    s_cm[wave][lane]  = cm;
    __syncthreads();
    if (wave == 0 && n < NN) {
        float a = fmaxf(fmaxf(s_ncm[0][lane], s_ncm[1][lane]),
                        fmaxf(s_ncm[2][lane], s_ncm[3][lane]));
        float c = fmaxf(fmaxf(s_cm[0][lane], s_cm[1][lane]),
                        fmaxf(s_cm[2][lane], s_cm[3][lane]));
        const float nc_max = vroi ? a : 0.0f;
        const float c_max  = vroi ? c : 0.0f;
        out[b * 2 * NN + n]      = nc_max;
        out[b * 2 * NN + NN + n] = c_max;
        const float pos = (vroi && nc_max >= 0.5f) ? 1.0f : 0.0f;
        const float neg = (vroi && nc_max < 0.5f && c_max < 0.001f) ? 1.0f : 0.0f;
        out[BB * 2 * NN + b * NN + n]           = pos;
        out[BB * 2 * NN + BB * NN + b * NN + n] = neg;
    }
}

extern "C" void kernel_launch(void* const* d_in, const int* in_sizes, int n_in,
                              void* d_out, int out_size, void* d_ws, size_t ws_size,
                              hipStream_t stream) {
    const float4* rois     = (const float4*)d_in[0];
    const int*    gt_ids   = (const int*)d_in[1];
    const float4* gt_boxes = (const float4*)d_in[2];
    float*        out      = (float*)d_out;

    if (ws_size >= (size_t)WS_NEEDED) {
        char* ws = (char*)d_ws;
        float4* ws_box  = (float4*)(ws + WS_BOX_OFF);
        float*  ws_area = (float*)(ws + WS_AREA_OFF);
        int*    ws_cnt  = (int*)(ws + WS_CNT_OFF);

        compact_kernel<<<BB, 256, 0, stream>>>(gt_ids, gt_boxes, ws_box, ws_area, ws_cnt);
        dim3 grid((NN + 63) / 64, BB);
        det_main_kernel<<<grid, 64 * WAVES, 0, stream>>>(
            rois, ws_box, ws_area, ws_cnt, out);
    } else {
        dim3 grid((NN + 63) / 64, BB);
        det_assign_fallback<<<grid, 256, 0, stream>>>(rois, gt_ids, gt_boxes, out);
    }
}

// Round 8
// 27.969 us; speedup vs baseline: 1.3527x; 1.1101x over previous
//
#include <hip/hip_runtime.h>

#define BB 16
#define NN 6000
#define GG 512
#define WAVES 8
#define ROIS_PER_BLOCK 128   // RPT=2: two 64-ROI slots per block

__global__ __launch_bounds__(64 * WAVES) void det_kernel(
    const float4* __restrict__ rois,      // (B, N, 4)
    const int*    __restrict__ gt_ids,    // (B, G)
    const float4* __restrict__ gt_boxes,  // (B, G, 4)
    float*        __restrict__ out)       // [B*2*N maxes][B*N pos][B*N neg]
{
    __shared__ float4 s_box[GG];             // nc from front, crowd from back
    __shared__ float4 s_area4[GG / 4];
    __shared__ float  s_ncm[WAVES][ROIS_PER_BLOCK];
    __shared__ float  s_cm[WAVES][ROIS_PER_BLOCK];
    __shared__ int    s_cnt[2];              // raw counts
    __shared__ int    s_bounds[2];           // nc_eff, lo_pad (x4-aligned)
    float* s_area = (float*)s_area4;

    const int b    = blockIdx.y;
    const int tid  = threadIdx.x;
    const int wave = tid >> 6;
    const int lane = tid & 63;

    if (tid == 0) { s_cnt[0] = 0; s_cnt[1] = 0; }
    __syncthreads();

    // ---- ballot compaction: one GT per thread (512 threads == GG) ----
    {
        const int g = tid;
        float4 box = gt_boxes[b * GG + g];
        float asum = fabsf(box.x) + fabsf(box.y) + fabsf(box.z) + fabsf(box.w);
        int id = gt_ids[b * GG + g];
        const bool pn = (asum > 0.0f) && (id > 0);
        const bool pc = (asum > 0.0f) && (id < 0);
        unsigned long long mn = __ballot(pn);
        unsigned long long mc = __ballot(pc);
        int bn = 0, bc = 0;
        if (lane == 0) {
            bn = atomicAdd(&s_cnt[0], __popcll(mn));
            bc = atomicAdd(&s_cnt[1], __popcll(mc));
        }
        bn = __shfl(bn, 0);
        bc = __shfl(bc, 0);
        const unsigned long long lt = (1ULL << lane) - 1ULL;
        if (pn) {
            int idx = bn + __popcll(mn & lt);
            s_box[idx]  = box;
            s_area[idx] = (box.z - box.x) * (box.w - box.y);
        }
        if (pc) {
            int idx = (GG - 1) - (bc + __popcll(mc & lt));
            s_box[idx]  = box;
            s_area[idx] = (box.z - box.x) * (box.w - box.y);
        }
    }
    __syncthreads();

    if (tid == 0) {
        int ncnt = s_cnt[0];
        int lo   = GG - s_cnt[1];
        int nc_eff = (ncnt + 3) & ~3;   // pad nc list up to x4
        int lo_pad = lo & ~3;           // pad crowd list down to x4
        if (nc_eff > lo_pad) nc_eff = lo_pad;
        s_bounds[0] = nc_eff;
        s_bounds[1] = lo_pad;
    }
    __syncthreads();

    const int nc_eff = s_bounds[0];
    const int lo_pad = s_bounds[1];

    // zero-fill pad slots (zero box => IoU 0, harmless for max)
    {
        const float4 z = make_float4(0.f, 0.f, 0.f, 0.f);
        const int ncnt = s_cnt[0];
        const int lo   = GG - s_cnt[1];
        if (tid < 4) {
            int i = ncnt + tid;
            if (i < nc_eff) { s_box[i] = z; s_area[i] = 0.f; }
        } else if (tid < 8) {
            int i = lo_pad + (tid - 4);
            if (i < lo) { s_box[i] = z; s_area[i] = 0.f; }
        }
    }
    __syncthreads();

    // ---- per-thread: 2 ROIs (slots lane and 64+lane) ----
    const int nbase = blockIdx.x * ROIS_PER_BLOCK;
    const int n0 = nbase + lane;
    const int n1 = nbase + 64 + lane;
    const float4 z4 = make_float4(0.f, 0.f, 0.f, 0.f);
    const float4 r0 = (n0 < NN) ? rois[b * NN + n0] : z4;
    const float4 r1 = (n1 < NN) ? rois[b * NN + n1] : z4;
    const bool  v0 = (fabsf(r0.x) + fabsf(r0.y) + fabsf(r0.z) + fabsf(r0.w)) > 0.0f;
    const bool  v1 = (fabsf(r1.x) + fabsf(r1.y) + fabsf(r1.z) + fabsf(r1.w)) > 0.0f;
    const float rs0 = (r0.z - r0.x) * (r0.w - r0.y) + 1e-8f;
    const float rs1 = (r1.z - r1.x) * (r1.w - r1.y) + 1e-8f;

    auto iou_of = [](const float4& rr, float rsum, const float4& g4, float ga) -> float {
        float yy1 = fmaxf(rr.x, g4.x);
        float xx1 = fmaxf(rr.y, g4.y);
        float yy2 = fminf(rr.z, g4.z);
        float xx2 = fminf(rr.w, g4.w);
        float inter = fmaxf(yy2 - yy1, 0.0f) * fmaxf(xx2 - xx1, 0.0f);
        float uni = rsum + ga - inter;
        return inter * __builtin_amdgcn_rcpf(uni);
    };

    float nc0 = 0.f, nc1 = 0.f, c0 = 0.f, c1 = 0.f;

    // ---- non-crowd: groups [0, nc_eff/4), split across 8 waves ----
    {
        const int ngr = nc_eff >> 2;
        const int gpw = (ngr + WAVES - 1) / WAVES;
        const int q0 = wave * gpw;
        const int q1 = min(ngr, q0 + gpw);
        for (int q = q0; q < q1; ++q) {
            float4 b0 = s_box[4 * q + 0];
            float4 b1 = s_box[4 * q + 1];
            float4 b2 = s_box[4 * q + 2];
            float4 b3 = s_box[4 * q + 3];
            float4 a4 = s_area4[q];
            nc0 = fmaxf(nc0, fmaxf(fmaxf(iou_of(r0, rs0, b0, a4.x), iou_of(r0, rs0, b1, a4.y)),
                                   fmaxf(iou_of(r0, rs0, b2, a4.z), iou_of(r0, rs0, b3, a4.w))));
            nc1 = fmaxf(nc1, fmaxf(fmaxf(iou_of(r1, rs1, b0, a4.x), iou_of(r1, rs1, b1, a4.y)),
                                   fmaxf(iou_of(r1, rs1, b2, a4.z), iou_of(r1, rs1, b3, a4.w))));
        }
    }
    // ---- crowd: groups [lo_pad/4, GG/4), split across 8 waves ----
    {
        const int cg0 = lo_pad >> 2;
        const int cgn = (GG >> 2) - cg0;
        const int gpw = (cgn + WAVES - 1) / WAVES;
        const int q0 = cg0 + wave * gpw;
        const int q1 = min(GG >> 2, q0 + gpw);
        for (int q = q0; q < q1; ++q) {
            float4 b0 = s_box[4 * q + 0];
            float4 b1 = s_box[4 * q + 1];
            float4 b2 = s_box[4 * q + 2];
            float4 b3 = s_box[4 * q + 3];
            float4 a4 = s_area4[q];
            c0 = fmaxf(c0, fmaxf(fmaxf(iou_of(r0, rs0, b0, a4.x), iou_of(r0, rs0, b1, a4.y)),
                                 fmaxf(iou_of(r0, rs0, b2, a4.z), iou_of(r0, rs0, b3, a4.w))));
            c1 = fmaxf(c1, fmaxf(fmaxf(iou_of(r1, rs1, b0, a4.x), iou_of(r1, rs1, b1, a4.y)),
                                 fmaxf(iou_of(r1, rs1, b2, a4.z), iou_of(r1, rs1, b3, a4.w))));
        }
    }

    s_ncm[wave][lane]      = nc0;
    s_ncm[wave][64 + lane] = nc1;
    s_cm[wave][lane]       = c0;
    s_cm[wave][64 + lane]  = c1;
    __syncthreads();

    // ---- reduce + write: wave 0 handles slot lane (its r0), wave 1 slot 64+lane (its r1) ----
    if (wave < 2) {
        const int i = wave * 64 + lane;       // ROI slot in block
        const int n = nbase + i;
        if (n < NN) {
            const bool  vr = (wave == 0) ? v0 : v1;
            float a = s_ncm[0][i], c = s_cm[0][i];
            #pragma unroll
            for (int w = 1; w < WAVES; ++w) {
                a = fmaxf(a, s_ncm[w][i]);
                c = fmaxf(c, s_cm[w][i]);
            }
            const float nc_max = vr ? a : 0.0f;
            const float c_max  = vr ? c : 0.0f;

            out[b * 2 * NN + n]      = nc_max;   // iou_maxes (B,2,N) ch0
            out[b * 2 * NN + NN + n] = c_max;    // iou_maxes (B,2,N) ch1
            const float pos = (vr && nc_max >= 0.5f) ? 1.0f : 0.0f;
            const float neg = (vr && nc_max < 0.5f && c_max < 0.001f) ? 1.0f : 0.0f;
            out[BB * 2 * NN + b * NN + n]           = pos;
            out[BB * 2 * NN + BB * NN + b * NN + n] = neg;
        }
    }
}

extern "C" void kernel_launch(void* const* d_in, const int* in_sizes, int n_in,
                              void* d_out, int out_size, void* d_ws, size_t ws_size,
                              hipStream_t stream) {
    const float4* rois     = (const float4*)d_in[0];
    const int*    gt_ids   = (const int*)d_in[1];
    const float4* gt_boxes = (const float4*)d_in[2];
    float*        out      = (float*)d_out;

    dim3 grid((NN + ROIS_PER_BLOCK - 1) / ROIS_PER_BLOCK, BB);  // 47 x 16
    det_kernel<<<grid, 64 * WAVES, 0, stream>>>(rois, gt_ids, gt_boxes, out);
}